// Round 17
// baseline (41.479 us; speedup 1.0000x reference)
//
#include <hip/hip_runtime.h>

// ============================================================================
// AttenPool: softmax-over-L summed over L == 1, so
//   out[b,c,P] = (1-a)*( sumpool4(conv3(BN(x),wv))[c,P] + 16*bv[c] )
//                + a*sumpool4(x)[c,P]
// == 6x6 stride-4 conv (W6) with BN scale folded in, per-channel alpha term on
// the weight diagonal, BN offset as per-(o, border-class) constant.
// Implicit GEMM on mfma_f32_16x16x32_bf16 (A/B share one (lane,elem)->(tap,ch)
// map so HW k-permutation cancels). LDS x tile [pixel][16ch] bf16, dbuf,
// bijective swizzle addr = (p*32+hh*16) ^ (((p>>2)&7)<<4).
// Round 17: per-CU vmem wave-instruction model (r5/r6, r9, r11/r12, r16):
// halve the count by doubling the tile. 32x32-px tile (r5's PASSED MFMA core:
// 4 N-tiles/wave, nt-address identities a1=(a0+8704)^64, a2=a0+17408) +
// r16's GLL staging (inverse-swizzled global srcoff, linear LDS dest).
// Per-CU vmem: 4 waves x (10 GLL + 18 AF) x 4 chunks = 448 (was 736).
// LDS 74KB dbuf -> 1 block/CU. k_pc byte-identical.
// ============================================================================

typedef short short8 __attribute__((ext_vector_type(8)));
typedef float f32x4 __attribute__((ext_vector_type(4)));

constexpr int Bn = 16, Cn = 64, Hn = 128, Wn = 128, NP = 32;
constexpr float EPSV = 1e-5f;
constexpr int PX = 1156;       // pixels per tile: 34 rows x 34 cols
constexpr int SLOTS = 2312;    // PX * 2 channel-halves

__device__ __forceinline__ unsigned short bf16r(float f) {
  unsigned u = __builtin_bit_cast(unsigned, f);
  u += 0x7fffu + ((u >> 16) & 1u);
  return (unsigned short)(u >> 16);
}

// ---- merged precompute + transpose ----
// blocks 0..15: WA weight table; block 16: offC; blocks 17..4112: x -> x_t cvt.
__global__ __launch_bounds__(256) void k_pc(const float* __restrict__ x,
                      const float* __restrict__ wv, const float* __restrict__ g0,
                      const float* __restrict__ b0, const float* __restrict__ m0,
                      const float* __restrict__ v0, const float* __restrict__ bv,
                      const float* __restrict__ alpha,
                      unsigned short* __restrict__ WA, float* __restrict__ offC,
                      unsigned short* __restrict__ xt) {
  __shared__ alignas(16) char lds[9216];
  const int idx = blockIdx.x;
  const int tid = threadIdx.x;

  if (idx >= 17) {
    // ---- cvt: x (NCHW fp32) -> x_t[b][cg][px][ch16] bf16, LDS transpose ----
    unsigned short* ts = (unsigned short*)lds;   // 256 px x 16 ch, swizzled
    const int cidx = idx - 17;
    const int pxb = cidx & 63, cg = (cidx >> 6) & 3, b = cidx >> 8;
    const int qd = tid & 63;
    const float* src = x + ((size_t)(b * 64 + cg * 16)) * 16384 + pxb * 256 + qd * 4;
    char* lb = (char*)ts;
#pragma unroll
    for (int j = 0; j < 4; ++j) {
      int k = (tid >> 6) + j * 4;
      float4 v = *(const float4*)(src + (size_t)k * 16384);
      int hh16 = (k >> 3) * 16, choff = (k & 7) * 2;
      float vv[4] = {v.x, v.y, v.z, v.w};
#pragma unroll
      for (int e = 0; e < 4; ++e) {
        int p = qd * 4 + e;
        int a = ((p * 32 + hh16) ^ (((p >> 2) & 7) << 4)) + choff;
        *(unsigned short*)(lb + a) = bf16r(vv[e]);
      }
    }
    __syncthreads();
    unsigned short* xo = xt + ((size_t)(b * 4 + cg) * 16384 + (size_t)pxb * 256) * 16;
#pragma unroll
    for (int j = 0; j < 2; ++j) {
      int s = tid + j * 256;
      int px = s >> 1, hh = s & 1;
      int a = (px * 32 + hh * 16) ^ (((px >> 2) & 7) << 4);
      short8 v = *(const short8*)(lb + a);
      *(short8*)(xo + (size_t)s * 8) = v;
    }
    return;
  }

  const float al = alpha[0];
  const float oma = 1.0f - al;
  if (idx < 16) {
    // ---- WA: short8 idx = s*1024 + chunk*256 + (mt*64 + g*16 + r)
    //      elem j: o = mt*16+r, tap t36 = 2s+(g>>1), i = chunk*16+(g&1)*8+j
    //      value = W6[o][i][t36]*s0[i]*(1-a) + a*delta_{o,i}*[tap interior]
    int t = idx * 256 + tid;   // t < 4096
    int o = t >> 6, i = t & 63;
    float s0 = g0[i] * rsqrtf(v0[i] + EPSV);
    float wl[3][3];
#pragma unroll
    for (int ky = 0; ky < 3; ++ky)
#pragma unroll
      for (int kx = 0; kx < 3; ++kx)
        wl[ky][kx] = wv[((o * Cn + i) * 3 + ky) * 3 + kx];
#pragma unroll
    for (int a = 0; a < 6; ++a) {
      int klo = (a - 3 < 0) ? 0 : a - 3, khi = (a < 2) ? a : 2;
#pragma unroll
      for (int b = 0; b < 6; ++b) {
        int llo = (b - 3 < 0) ? 0 : b - 3, lhi = (b < 2) ? b : 2;
        float s = 0.f;
        for (int ky = klo; ky <= khi; ++ky)
          for (int kx = llo; kx <= lhi; ++kx) s += wl[ky][kx];
        float val = s * s0 * oma;
        if (o == i && a >= 1 && a <= 4 && b >= 1 && b <= 4) val += al;
        int t36 = a * 6 + b;
        int g = (t36 & 1) * 2 + ((i >> 3) & 1);
        int idx8 = (t36 >> 1) * 1024 + (i >> 4) * 256 + ((o >> 4) * 64 + g * 16 + (o & 15));
        WA[idx8 * 8 + (i & 7)] = bf16r(val);
      }
    }
  } else {
    // ---- offC[cls][o]: phase 1 = per-(o, i-group) tap partials ----
    float (*red)[64][9] = (float(*)[64][9])lds;
    const int o = tid & 63, q = tid >> 6;
    float P[9] = {0.f, 0.f, 0.f, 0.f, 0.f, 0.f, 0.f, 0.f, 0.f};
#pragma unroll 4
    for (int ii = 0; ii < 16; ++ii) {
      int i = q * 16 + ii;
      float s0 = g0[i] * rsqrtf(v0[i] + EPSV);
      float o0 = b0[i] - m0[i] * s0;
      const float* wp = wv + ((size_t)o * 64 + i) * 9;
#pragma unroll
      for (int kk = 0; kk < 9; ++kk) P[kk] += o0 * wp[kk];
    }
#pragma unroll
    for (int kk = 0; kk < 9; ++kk) red[q][o][kk] = P[kk];
    __syncthreads();
    const float NT[3][3] = {{3.f, 4.f, 4.f}, {4.f, 4.f, 4.f}, {4.f, 4.f, 3.f}};
    for (int i2 = tid; i2 < 576; i2 += 256) {
      int cls = i2 >> 6, o2 = i2 & 63;
      int ic = cls / 3, jc = cls % 3;
      float s = 0.f;
#pragma unroll
      for (int ky = 0; ky < 3; ++ky)
#pragma unroll
        for (int kx = 0; kx < 3; ++kx) {
          int kk = ky * 3 + kx;
          float Pv = (red[0][o2][kk] + red[1][o2][kk]) + (red[2][o2][kk] + red[3][o2][kk]);
          s += Pv * NT[ic][ky] * NT[jc][kx];
        }
      offC[cls * 64 + o2] = oma * (s + 16.f * bv[o2]);
    }
  }
}

// ---- fused MFMA conv (+ diag alpha term) + offset epilogue ----
// Block: batch b, 8x8 patch tile (32x32 px + halo -> 34x34), 64 out-ch.
// 4 waves = 4 o-groups; each wave covers 4 N-tiles (nt = 0..3).
__global__ __launch_bounds__(256, 1) void k_conv(const unsigned short* __restrict__ xt,
    const unsigned short* __restrict__ WA, const float* __restrict__ offC,
    float* __restrict__ out) {
  __shared__ alignas(128) unsigned short xs[2][SLOTS * 8];  // 2 x 36992 B

  const int tid = threadIdx.x;
  const int b = blockIdx.z, by = blockIdx.y, bx = blockIdx.x;
  const int lane = tid & 63, w = tid >> 6;
  const int r = lane & 15, g = lane >> 4;       // g in 0..3
  const int g1 = g >> 1, hh16 = (g & 1) * 16;
  const char* xtb = (const char*)xt + (size_t)b * 2097152;  // b-plane (4 cg)
  const int grow0 = by * 32 - 1, gcol0 = bx * 32 - 1;

  // source offsets: dest slot s (linear) -> inverse-swizzle -> (p,hh) -> x_t
  // slot mask: s < 2312 -> j<9 full, j==9 only tid<8
  int srcoff[10];
#pragma unroll
  for (int j = 0; j < 10; ++j) {
    int s = tid + j * 256;
    int L = s << 4;
    int f = (L >> 7) & 7;
    int orig = L ^ (f << 4);
    int p = orig >> 5, hh = (orig >> 4) & 1;
    int rr = p / 34, cc = p - rr * 34;
    int gr = grow0 + rr, gc = gcol0 + cc;
    bool inb = ((unsigned)gr < 128u) && ((unsigned)gc < 128u);
    srcoff[j] = inb ? ((gr * 128 + gc) * 32 + hh * 16) : -1;
  }

  // B-frag base: patch P = nt*16 + r -> pi = nt*2 + (r>>3), pj = r&7
  // pixel(nt) = pbase + nt*272 + tap offset
  const int pbase = (r >> 3) * 136 + (r & 7) * 4 + g1;

  f32x4 acc[4];  // [nt]
#pragma unroll
  for (int t = 0; t < 4; ++t)
#pragma unroll
    for (int i = 0; i < 4; ++i) acc[t][i] = 0.f;
  short8 af[18];

  auto AFLOAD = [&](int ch) {
    const short8* wv8 = (const short8*)WA;
    const int lc = ch * 256 + tid;  // = ch*256 + w*64 + g*16 + r
#pragma unroll
    for (int s = 0; s < 18; ++s) af[s] = wv8[s * 1024 + lc];
  };
  // pre-zero chunk-invariant invalid (halo) slots in BOTH buffers, once
  auto PREZERO = [&]() {
    short8 z = (short8)(short)0;
#pragma unroll
    for (int j = 0; j < 10; ++j) {
      if ((j < 9 || tid < 8) && srcoff[j] < 0) {
        *(short8*)((char*)&xs[0][0] + (tid + j * 256) * 16) = z;
        *(short8*)((char*)&xs[1][0] + (tid + j * 256) * 16) = z;
      }
    }
  };
  // async global->LDS staging: linear dest (wave base + lane*16), swizzled src
  auto GLL = [&](int cg, int buf) {
    const char* base = xtb + (size_t)cg * 524288;
    char* lb = (char*)&xs[buf & 1][0] + (size_t)(w * 64) * 16;  // wave-uniform
#pragma unroll
    for (int j = 0; j < 10; ++j) {
      if ((j < 9 || tid < 8) && srcoff[j] >= 0) {
        __builtin_amdgcn_global_load_lds(
            (const __attribute__((address_space(1))) void*)(base + srcoff[j]),
            (__attribute__((address_space(3))) void*)(lb + j * 4096), 16, 0, 0);
      }
    }
  };
  auto MFMA = [&](int ch) {
    const char* base = (const char*)&xs[ch & 1][0];
#pragma unroll
    for (int s = 0; s < 18; ++s) {
      const int toff = ((2 * s) / 6) * 34 + (2 * s) % 6;  // compile-time
      int p = pbase + toff;
      int a0 = (p * 32) ^ (((p >> 2) & 7) << 4) ^ hh16;
      int a1 = (a0 + 8704) ^ 64;          // swz(p+272) identity
      int a2 = a0 + 17408;                // swz(p+544) identity
      int a3 = (a2 + 8704) ^ 64;
      short8 bv0 = *(const short8*)(base + a0);
      short8 bv1 = *(const short8*)(base + a1);
      short8 bv2 = *(const short8*)(base + a2);
      short8 bv3 = *(const short8*)(base + a3);
      acc[0] = __builtin_amdgcn_mfma_f32_16x16x32_bf16(af[s], bv0, acc[0], 0, 0, 0);
      acc[1] = __builtin_amdgcn_mfma_f32_16x16x32_bf16(af[s], bv1, acc[1], 0, 0, 0);
      acc[2] = __builtin_amdgcn_mfma_f32_16x16x32_bf16(af[s], bv2, acc[2], 0, 0, 0);
      acc[3] = __builtin_amdgcn_mfma_f32_16x16x32_bf16(af[s], bv3, acc[3], 0, 0, 0);
    }
  };

  PREZERO();
  GLL(0, 0);
  __syncthreads();                          // vmcnt(0)+lgkmcnt(0) drain: buf0 ready
#pragma unroll
  for (int c = 0; c < 4; ++c) {
    AFLOAD(c);                              // 18 L2 loads first (oldest in FIFO
    __builtin_amdgcn_sched_barrier(0);      //  -> af waits never drain staging)
    if (c < 3) GLL(c + 1, c + 1);           // 10 async dwordx4 direct-to-LDS
    __builtin_amdgcn_sched_barrier(0);
    MFMA(c);                                // af-wait leaves GLLs in flight
    if (c < 3) __syncthreads();             // drains GLL -> next buffer ready
  }

  // epilogue: D col = lane&15 = r -> patch P = nt*16+r; row = g*4+reg -> o
#pragma unroll
  for (int nt = 0; nt < 4; ++nt) {
    const int P = nt * 16 + r;
    const int pig = by * 8 + (P >> 3), pjg = bx * 8 + (P & 7);
    const int icl = (pig == 0) ? 0 : ((pig == 31) ? 2 : 1);
    const int jcl = (pjg == 0) ? 0 : ((pjg == 31) ? 2 : 1);
    const float* offr = offC + (icl * 3 + jcl) * 64;
    float* ob = out + (((size_t)b * 64) * NP + pig) * NP + pjg;
#pragma unroll
    for (int reg = 0; reg < 4; ++reg) {
      const int o = w * 16 + g * 4 + reg;
      ob[(size_t)o * 1024] = acc[nt][reg] + offr[o];
    }
  }
}

extern "C" void kernel_launch(void* const* d_in, const int* in_sizes, int n_in,
                              void* d_out, int out_size, void* d_ws, size_t ws_size,
                              hipStream_t stream) {
  const float* x     = (const float*)d_in[0];
  const float* g0    = (const float*)d_in[1];
  const float* b0    = (const float*)d_in[2];
  const float* m0    = (const float*)d_in[3];
  const float* v0    = (const float*)d_in[4];
  const float* wv    = (const float*)d_in[15];
  const float* bv    = (const float*)d_in[16];
  const float* alpha = (const float*)d_in[17];
  float* out = (float*)d_out;

  unsigned short* WA = (unsigned short*)d_ws;              // 288 KB at offset 0
  float* offC = (float*)((char*)d_ws + 294912);            // 9*64 floats
  unsigned short* xt = (unsigned short*)((char*)d_ws + 524288);  // 32 MiB

  k_pc<<<4113, 256, 0, stream>>>(x, wv, g0, b0, m0, v0, bv, alpha, WA, offC, xt);
  dim3 grid(NP / 8, NP / 8, Bn);
  k_conv<<<grid, 256, 0, stream>>>(xt, WA, offC, out);
}

// Round 18
// 39.197 us; speedup vs baseline: 1.0582x; 1.0582x over previous
//
#include <hip/hip_runtime.h>

// ============================================================================
// AttenPool: softmax-over-L summed over L == 1, so
//   out[b,c,P] = (1-a)*( sumpool4(conv3(BN(x),wv))[c,P] + 16*bv[c] )
//                + a*sumpool4(x)[c,P]
// == 6x6 stride-4 conv (W6) with BN scale folded in, per-channel alpha term on
// the weight diagonal, BN offset as per-(o, border-class) constant.
// Implicit GEMM on mfma_f32_16x16x32_bf16 (A/B share one (lane,elem)->(tap,ch)
// map so HW k-permutation cancels). LDS x tile [pixel][16ch] bf16, dbuf,
// bijective swizzle addr = (p*32+hh*16) ^ (((p>>2)&7)<<4).
// Round 18: FINAL — restore r15 (best validated, 39.2us). Experiment ladder:
// r11 8-wave (-3.3us), r12 ds-dedup (flat), r13 single-pass (-23us), r16
// global_load_lds (flat), r17 2x-tile/half-vmem (-2.3us) => r10/r15 config is
// the measured optimum: k_pc 4096-block transpose stream @80% HBM (its
// roofline) + k_conv 5 coalesced short8 + 5 linear ds_write_b128 staging,
// AF-first vmcnt FIFO, ~13.5us floor across all staging variants.
// ============================================================================

typedef short short8 __attribute__((ext_vector_type(8)));
typedef float f32x4 __attribute__((ext_vector_type(4)));

constexpr int Bn = 16, Cn = 64, Hn = 128, Wn = 128, NP = 32;
constexpr float EPSV = 1e-5f;
constexpr int PX = 612;        // pixels per tile: 18 rows x 34 cols
constexpr int SLOTS = 1224;    // PX * 2 channel-halves

__device__ __forceinline__ unsigned short bf16r(float f) {
  unsigned u = __builtin_bit_cast(unsigned, f);
  u += 0x7fffu + ((u >> 16) & 1u);
  return (unsigned short)(u >> 16);
}

// ---- merged precompute + transpose ----
// blocks 0..15: WA weight table; block 16: offC; blocks 17..4112: x -> x_t cvt.
__global__ __launch_bounds__(256) void k_pc(const float* __restrict__ x,
                      const float* __restrict__ wv, const float* __restrict__ g0,
                      const float* __restrict__ b0, const float* __restrict__ m0,
                      const float* __restrict__ v0, const float* __restrict__ bv,
                      const float* __restrict__ alpha,
                      unsigned short* __restrict__ WA, float* __restrict__ offC,
                      unsigned short* __restrict__ xt) {
  __shared__ alignas(16) char lds[9216];
  const int idx = blockIdx.x;
  const int tid = threadIdx.x;

  if (idx >= 17) {
    // ---- cvt: x (NCHW fp32) -> x_t[b][cg][px][ch16] bf16, LDS transpose ----
    unsigned short* ts = (unsigned short*)lds;   // 256 px x 16 ch, swizzled
    const int cidx = idx - 17;
    const int pxb = cidx & 63, cg = (cidx >> 6) & 3, b = cidx >> 8;
    const int qd = tid & 63;
    const float* src = x + ((size_t)(b * 64 + cg * 16)) * 16384 + pxb * 256 + qd * 4;
    char* lb = (char*)ts;
#pragma unroll
    for (int j = 0; j < 4; ++j) {
      int k = (tid >> 6) + j * 4;
      float4 v = *(const float4*)(src + (size_t)k * 16384);
      int hh16 = (k >> 3) * 16, choff = (k & 7) * 2;
      float vv[4] = {v.x, v.y, v.z, v.w};
#pragma unroll
      for (int e = 0; e < 4; ++e) {
        int p = qd * 4 + e;
        int a = ((p * 32 + hh16) ^ (((p >> 2) & 7) << 4)) + choff;
        *(unsigned short*)(lb + a) = bf16r(vv[e]);
      }
    }
    __syncthreads();
    unsigned short* xo = xt + ((size_t)(b * 4 + cg) * 16384 + (size_t)pxb * 256) * 16;
#pragma unroll
    for (int j = 0; j < 2; ++j) {
      int s = tid + j * 256;
      int px = s >> 1, hh = s & 1;
      int a = (px * 32 + hh * 16) ^ (((px >> 2) & 7) << 4);
      short8 v = *(const short8*)(lb + a);
      *(short8*)(xo + (size_t)s * 8) = v;
    }
    return;
  }

  const float al = alpha[0];
  const float oma = 1.0f - al;
  if (idx < 16) {
    // ---- WA: short8 idx = s*1024 + chunk*256 + (mt*64 + g*16 + r)
    //      elem j: o = mt*16+r, tap t36 = 2s+(g>>1), i = chunk*16+(g&1)*8+j
    //      value = W6[o][i][t36]*s0[i]*(1-a) + a*delta_{o,i}*[tap interior]
    int t = idx * 256 + tid;   // t < 4096
    int o = t >> 6, i = t & 63;
    float s0 = g0[i] * rsqrtf(v0[i] + EPSV);
    float wl[3][3];
#pragma unroll
    for (int ky = 0; ky < 3; ++ky)
#pragma unroll
      for (int kx = 0; kx < 3; ++kx)
        wl[ky][kx] = wv[((o * Cn + i) * 3 + ky) * 3 + kx];
#pragma unroll
    for (int a = 0; a < 6; ++a) {
      int klo = (a - 3 < 0) ? 0 : a - 3, khi = (a < 2) ? a : 2;
#pragma unroll
      for (int b = 0; b < 6; ++b) {
        int llo = (b - 3 < 0) ? 0 : b - 3, lhi = (b < 2) ? b : 2;
        float s = 0.f;
        for (int ky = klo; ky <= khi; ++ky)
          for (int kx = llo; kx <= lhi; ++kx) s += wl[ky][kx];
        float val = s * s0 * oma;
        if (o == i && a >= 1 && a <= 4 && b >= 1 && b <= 4) val += al;
        int t36 = a * 6 + b;
        int g = (t36 & 1) * 2 + ((i >> 3) & 1);
        int idx8 = (t36 >> 1) * 1024 + (i >> 4) * 256 + ((o >> 4) * 64 + g * 16 + (o & 15));
        WA[idx8 * 8 + (i & 7)] = bf16r(val);
      }
    }
  } else {
    // ---- offC[cls][o]: phase 1 = per-(o, i-group) tap partials ----
    float (*red)[64][9] = (float(*)[64][9])lds;
    const int o = tid & 63, q = tid >> 6;
    float P[9] = {0.f, 0.f, 0.f, 0.f, 0.f, 0.f, 0.f, 0.f, 0.f};
#pragma unroll 4
    for (int ii = 0; ii < 16; ++ii) {
      int i = q * 16 + ii;
      float s0 = g0[i] * rsqrtf(v0[i] + EPSV);
      float o0 = b0[i] - m0[i] * s0;
      const float* wp = wv + ((size_t)o * 64 + i) * 9;
#pragma unroll
      for (int kk = 0; kk < 9; ++kk) P[kk] += o0 * wp[kk];
    }
#pragma unroll
    for (int kk = 0; kk < 9; ++kk) red[q][o][kk] = P[kk];
    __syncthreads();
    const float NT[3][3] = {{3.f, 4.f, 4.f}, {4.f, 4.f, 4.f}, {4.f, 4.f, 3.f}};
    for (int i2 = tid; i2 < 576; i2 += 256) {
      int cls = i2 >> 6, o2 = i2 & 63;
      int ic = cls / 3, jc = cls % 3;
      float s = 0.f;
#pragma unroll
      for (int ky = 0; ky < 3; ++ky)
#pragma unroll
        for (int kx = 0; kx < 3; ++kx) {
          int kk = ky * 3 + kx;
          float Pv = (red[0][o2][kk] + red[1][o2][kk]) + (red[2][o2][kk] + red[3][o2][kk]);
          s += Pv * NT[ic][ky] * NT[jc][kx];
        }
      offC[cls * 64 + o2] = oma * (s + 16.f * bv[o2]);
    }
  }
}

// ---- fused MFMA conv (+ diag alpha term) + offset epilogue ----
// Block: batch b, 4x8 patch tile (16x32 px + halo -> 18x34), 64 out-ch.
__global__ __launch_bounds__(256, 2) void k_conv(const unsigned short* __restrict__ xt,
    const unsigned short* __restrict__ WA, const float* __restrict__ offC,
    float* __restrict__ out) {
  __shared__ alignas(128) unsigned short xs[2][SLOTS * 8];  // 2 x 19584 B

  const int tid = threadIdx.x;
  const int b = blockIdx.z, by = blockIdx.y, bx = blockIdx.x;
  const int lane = tid & 63, w = tid >> 6;
  const int r = lane & 15, g = lane >> 4;       // g in 0..3
  const int g1 = g >> 1, hh16 = (g & 1) * 16;
  const char* xtb = (const char*)xt + (size_t)b * 2097152;  // b-plane (4 cg)
  const int grow0 = by * 16 - 1, gcol0 = bx * 32 - 1;

  // source offsets: dest slot s (linear) -> inverse-swizzle -> (p,hh) -> x_t
  int srcoff[5];
#pragma unroll
  for (int j = 0; j < 5; ++j) {
    int s = tid + j * 256;
    int L = s << 4;
    int f = (L >> 7) & 7;
    int orig = L ^ (f << 4);
    int p = orig >> 5, hh = (orig >> 4) & 1;
    int rr = p / 34, cc = p - rr * 34;
    int gr = grow0 + rr, gc = gcol0 + cc;
    bool inb = ((unsigned)gr < 128u) && ((unsigned)gc < 128u);
    srcoff[j] = inb ? ((gr * 128 + gc) * 32 + hh * 16) : -1;
  }

  // B-frag base: patch P = nt*16 + r -> pi = nt*2 + (r>>3), pj = r&7
  const int pbase = (r >> 3) * 136 + (r & 7) * 4 + g1;

  f32x4 acc[4];  // [parity*2 + nt]
#pragma unroll
  for (int t = 0; t < 4; ++t)
#pragma unroll
    for (int i = 0; i < 4; ++i) acc[t][i] = 0.f;
  short8 st[5];
  short8 af[18];

  auto AFLOAD = [&](int ch) {
    const short8* wv8 = (const short8*)WA;
    const int lc = ch * 256 + tid;  // = ch*256 + w*64 + g*16 + r
#pragma unroll
    for (int s = 0; s < 18; ++s) af[s] = wv8[s * 1024 + lc];
  };
  auto LOAD = [&](int cg) {
    const char* base = xtb + (size_t)cg * 524288;
#pragma unroll
    for (int j = 0; j < 5; ++j) {
      if (j < 4 || tid < SLOTS - 1024) {
        st[j] = (srcoff[j] >= 0) ? *(const short8*)(base + srcoff[j])
                                 : (short8)(short)0;
      }
    }
  };
  auto WRITE = [&](int buf) {
    char* lb = (char*)&xs[buf & 1][0];
#pragma unroll
    for (int j = 0; j < 5; ++j)
      if (j < 4 || tid < SLOTS - 1024)
        *(short8*)(lb + (tid + j * 256) * 16) = st[j];
  };
  auto MFMA = [&](int ch) {
    const char* base = (const char*)&xs[ch & 1][0];
#pragma unroll
    for (int s = 0; s < 18; ++s) {
      const int toff = ((2 * s) / 6) * 34 + (2 * s) % 6;  // compile-time
      int p = pbase + toff;
      int a0 = (p * 32) ^ (((p >> 2) & 7) << 4) ^ hh16;
      int a1 = (a0 + 8704) ^ 64;          // swz(p+272) identity
      short8 bv0 = *(const short8*)(base + a0);
      short8 bv1 = *(const short8*)(base + a1);
      const int q = (s & 1) * 2;
      acc[q + 0] = __builtin_amdgcn_mfma_f32_16x16x32_bf16(af[s], bv0, acc[q + 0], 0, 0, 0);
      acc[q + 1] = __builtin_amdgcn_mfma_f32_16x16x32_bf16(af[s], bv1, acc[q + 1], 0, 0, 0);
    }
  };

  LOAD(0);
  WRITE(0);
  __syncthreads();
#pragma unroll
  for (int c = 0; c < 4; ++c) {
    AFLOAD(c);                              // 18 L2 loads first (oldest in FIFO
    __builtin_amdgcn_sched_barrier(0);      //  -> af waits never drain staging)
    if (c < 3) LOAD(c + 1);                 // 5 coalesced short8 loads
    __builtin_amdgcn_sched_barrier(0);
    MFMA(c);
    if (c < 3) {
      WRITE(c + 1);                         // 5 linear ds_write_b128
      __syncthreads();
    }
  }

  // epilogue: D col = lane&15 = r -> patch P = nt*16+r; row = g*4+reg -> o
  // acc layout is [parity*2 + nt] -> sum acc[nt] (parity 0) + acc[2+nt] (parity 1)
#pragma unroll
  for (int nt = 0; nt < 2; ++nt) {
    const int P = nt * 16 + r;
    const int pig = by * 4 + (P >> 3), pjg = bx * 8 + (P & 7);
    const int icl = (pig == 0) ? 0 : ((pig == 31) ? 2 : 1);
    const int jcl = (pjg == 0) ? 0 : ((pjg == 31) ? 2 : 1);
    const float* offr = offC + (icl * 3 + jcl) * 64;
    float* ob = out + (((size_t)b * 64) * NP + pig) * NP + pjg;
#pragma unroll
    for (int reg = 0; reg < 4; ++reg) {
      const int o = w * 16 + g * 4 + reg;
      float v = acc[nt][reg] + acc[2 + nt][reg];
      ob[(size_t)o * 1024] = v + offr[o];
    }
  }
}

extern "C" void kernel_launch(void* const* d_in, const int* in_sizes, int n_in,
                              void* d_out, int out_size, void* d_ws, size_t ws_size,
                              hipStream_t stream) {
  const float* x     = (const float*)d_in[0];
  const float* g0    = (const float*)d_in[1];
  const float* b0    = (const float*)d_in[2];
  const float* m0    = (const float*)d_in[3];
  const float* v0    = (const float*)d_in[4];
  const float* wv    = (const float*)d_in[15];
  const float* bv    = (const float*)d_in[16];
  const float* alpha = (const float*)d_in[17];
  float* out = (float*)d_out;

  unsigned short* WA = (unsigned short*)d_ws;              // 288 KB at offset 0
  float* offC = (float*)((char*)d_ws + 294912);            // 9*64 floats
  unsigned short* xt = (unsigned short*)((char*)d_ws + 524288);  // 32 MiB

  k_pc<<<4113, 256, 0, stream>>>(x, wv, g0, b0, m0, v0, bv, alpha, WA, offC, xt);
  dim3 grid(NP / 8, NP / 4, Bn);
  k_conv<<<grid, 256, 0, stream>>>(xt, WA, offC, out);
}